// Round 7
// baseline (155.555 us; speedup 1.0000x reference)
//
#include <hip/hip_runtime.h>

#define BB 32
#define SS 1024
#define EE 256

typedef float f4 __attribute__((ext_vector_type(4)));
typedef int   i4 __attribute__((ext_vector_type(4)));

// Single-pass length regulator. One block (256 thr = 4 waves) per 4 output/input
// row indices; blockIdx.y = batch. Each block recomputes the batch's duration
// cumsum in-block (4 KB coalesced load, L2-resident across the 925 blocks that
// share it) -> no separate cumsum kernel, no serialization bubble.
//  - wave w, row t = blockIdx.x*4 + w:
//      t < SS:        scatter x[b,t] into out rows [cum[t-1], cum[t]), nt stores
//      t >= mel_len:  zero-fill out row t, mask=1
__global__ void lr_onepass_kernel(const float* __restrict__ x,
                                  const int* __restrict__ dur,
                                  float* __restrict__ out,
                                  float* __restrict__ mask,
                                  int max_mel) {
    __shared__ int scum[SS];
    __shared__ int wtot[4];
    const int b = blockIdx.y;
    const int tid = threadIdx.x;
    const int lane = tid & 63;
    const int wave = tid >> 6;

    // ---- block-wide inclusive scan of duration[b, 0..1024) ----
    const i4 d = ((const i4*)(dur + b * SS))[tid];   // coalesced 4 KB/block
    const int s0 = d.x;
    const int s1 = s0 + d.y;
    const int s2 = s1 + d.z;
    const int s3 = s2 + d.w;
    int inc = s3;                                    // wave scan of thread sums
    for (int dd = 1; dd < 64; dd <<= 1) {
        const int y = __shfl_up(inc, dd, 64);
        if (lane >= dd) inc += y;
    }
    if (lane == 63) wtot[wave] = inc;
    __syncthreads();
    int woff = 0;
#pragma unroll
    for (int w = 0; w < 4; ++w) woff += (w < wave) ? wtot[w] : 0;
    const int toff = woff + inc - s3;                // exclusive prefix, this thread
    scum[tid * 4 + 0] = toff + s0;
    scum[tid * 4 + 1] = toff + s1;
    scum[tid * 4 + 2] = toff + s2;
    scum[tid * 4 + 3] = toff + s3;
    const int mel_len = wtot[0] + wtot[1] + wtot[2] + wtot[3];
    __syncthreads();

    // ---- scatter / tail, one row per wave ----
    const int t = blockIdx.x * 4 + wave;
    f4* obase = (f4*)(out + (size_t)b * max_mel * EE);
    float* mrow = mask + (size_t)b * max_mel;

    if (t < SS) {
        const int c1 = scum[t];                      // LDS broadcast, conflict-free
        const int c0 = t ? scum[t - 1] : 0;
        if (c1 > c0) {
            const f4* xrow = (const f4*)(x + ((size_t)b * SS + t) * EE);
            const f4 v = __builtin_nontemporal_load(xrow + lane);
            for (int tt = c0; tt < c1; ++tt)         // <=7 independent 1KB stores
                __builtin_nontemporal_store(v, obase + (size_t)tt * (EE / 4) + lane);
            if (lane < c1 - c0) mrow[c0 + lane] = 0.0f;
        }
    }
    if (t >= mel_len && t < max_mel) {
        const f4 z = {0.f, 0.f, 0.f, 0.f};
        __builtin_nontemporal_store(z, obase + (size_t)t * (EE / 4) + lane);
        if (lane == 0) mrow[t] = 1.0f;
    }
}

extern "C" void kernel_launch(void* const* d_in, const int* in_sizes, int n_in,
                              void* d_out, int out_size, void* d_ws, size_t ws_size,
                              hipStream_t stream) {
    const float* x   = (const float*)d_in[0];
    const int*   dur = (const int*)d_in[1];
    float* out = (float*)d_out;

    const int max_mel = out_size / (BB * (EE + 1));
    float* mask = out + (size_t)BB * max_mel * EE;

    const int span = (max_mel > SS) ? max_mel : SS;
    dim3 grid((span + 3) / 4, BB);
    lr_onepass_kernel<<<grid, 256, 0, stream>>>(x, dur, out, mask, max_mel);
}

// Round 8
// 144.947 us; speedup vs baseline: 1.0732x; 1.0732x over previous
//
#include <hip/hip_runtime.h>

#define BB 32
#define SS 1024
#define EE 256

typedef float f4 __attribute__((ext_vector_type(4)));
typedef int   i4 __attribute__((ext_vector_type(4)));

// One block (256 thr = 4 waves) per batch row: inclusive cumsum of duration.
// i4 loads, per-thread serial scan, wave shfl scan, 4-entry LDS combine.
__global__ void lr_cumsum_kernel(const int* __restrict__ dur, int* __restrict__ cum) {
    __shared__ int wtot[4];
    const int b = blockIdx.x;
    const int tid = threadIdx.x;
    const int lane = tid & 63;
    const int wave = tid >> 6;

    const i4 d = ((const i4*)(dur + b * SS))[tid];
    const int s0 = d.x;
    const int s1 = s0 + d.y;
    const int s2 = s1 + d.z;
    const int s3 = s2 + d.w;
    int inc = s3;
    for (int dd = 1; dd < 64; dd <<= 1) {
        const int y = __shfl_up(inc, dd, 64);
        if (lane >= dd) inc += y;
    }
    if (lane == 63) wtot[wave] = inc;
    __syncthreads();
    int woff = 0;
#pragma unroll
    for (int w = 0; w < 4; ++w) woff += (w < wave) ? wtot[w] : 0;
    const int toff = woff + inc - s3;
    i4 o; o.x = toff + s0; o.y = toff + s1; o.z = toff + s2; o.w = toff + s3;
    ((i4*)(cum + b * SS))[tid] = o;
}

// Fused scatter + tail (R4 structure). A/B change vs R4: REGULAR stores for
// out/mask (write-back, let L2/L3 absorb and drain lazily) instead of
// nontemporal; keep nt load for x (read-once).
__global__ void lr_fused_kernel(const float* __restrict__ x,
                                const int* __restrict__ cum,
                                float* __restrict__ out,
                                float* __restrict__ mask,
                                int max_mel) {
    const int b = blockIdx.y;
    const int wave = threadIdx.x >> 6;      // 4 waves/block
    const int lane = threadIdx.x & 63;
    const int t = blockIdx.x * 4 + wave;

    const int* crow = cum + b * SS;
    const int mel_len = crow[SS - 1];
    f4* obase = (f4*)(out + (size_t)b * max_mel * EE);
    float* mrow = mask + (size_t)b * max_mel;

    if (t < SS) {
        const int c1 = crow[t];
        const int c0 = (t == 0) ? 0 : crow[t - 1];
        if (c1 > c0) {
            const f4* xrow = (const f4*)(x + ((size_t)b * SS + t) * EE);
            const f4 v = __builtin_nontemporal_load(xrow + lane);
            for (int tt = c0; tt < c1; ++tt)
                obase[(size_t)tt * (EE / 4) + lane] = v;
            if (lane < c1 - c0) mrow[c0 + lane] = 0.0f;
        }
    }
    if (t >= mel_len && t < max_mel) {
        const f4 z = {0.f, 0.f, 0.f, 0.f};
        obase[(size_t)t * (EE / 4) + lane] = z;
        if (lane == 0) mrow[t] = 1.0f;
    }
}

extern "C" void kernel_launch(void* const* d_in, const int* in_sizes, int n_in,
                              void* d_out, int out_size, void* d_ws, size_t ws_size,
                              hipStream_t stream) {
    const float* x   = (const float*)d_in[0];
    const int*   dur = (const int*)d_in[1];
    float* out = (float*)d_out;

    const int max_mel = out_size / (BB * (EE + 1));
    float* mask = out + (size_t)BB * max_mel * EE;
    int* cum = (int*)d_ws;                  // 128 KB scratch

    lr_cumsum_kernel<<<BB, 256, 0, stream>>>(dur, cum);

    const int span = (max_mel > SS) ? max_mel : SS;
    dim3 grid((span + 3) / 4, BB);
    lr_fused_kernel<<<grid, 256, 0, stream>>>(x, cum, out, mask, max_mel);
}